// Round 1
// baseline (908.652 us; speedup 1.0000x reference)
//
#include <hip/hip_runtime.h>
#include <math.h>

#define MX 512
#define NY 512
#define TWO_PI 6.283185307179586f

// ---------------------------------------------------------------------------
// Cos DCT matrix: C[a][j] = cos(pi * a * (2j+1) / (2*512)).
// mx == ny == 512, so one matrix serves both dims.
// a*(2j+1) < 2^20 so exact in fp32; /1024 exact; cospif does the reduction.
// ---------------------------------------------------------------------------
__global__ void gen_cos_kernel(float* __restrict__ C) {
    int idx = blockIdx.x * blockDim.x + threadIdx.x;   // idx = a*512 + j
    int a = idx >> 9;
    int j = idx & 511;
    float x = (float)(a * (2 * j + 1)) * (1.0f / 1024.0f);
    C[idx] = cospif(x);
}

// ---------------------------------------------------------------------------
// Scatter: per node compute pre_normalize, then atomicAdd its 4x4 overlap
// footprint into dm. Zero contributions are skipped (spans are 1.41..2.5
// bins, so typically only 2-3 columns/rows are nonzero).
// ---------------------------------------------------------------------------
__global__ void scatter_kernel(const float2* __restrict__ pos,
                               const float2* __restrict__ size,
                               const float* __restrict__ nwt,
                               const float* __restrict__ er,
                               const float* __restrict__ unit_len,
                               float* __restrict__ dm, int n) {
    int i = blockIdx.x * blockDim.x + threadIdx.x;
    if (i >= n) return;

    float ux = unit_len[0], uy = unit_len[1];
    const float SQ2 = 1.41421356237309515f;

    float2 p = pos[i];
    float2 s = size[i];
    float nw = fmaxf(s.x, SQ2 * ux);
    float nh = fmaxf(s.y, SQ2 * uy);
    float w  = nwt[i] * er[i] * (s.x * s.y) / (nw * nh);

    float xl = fminf(fmaxf((p.x - 0.5f * nw) / ux, 0.0f), (float)MX);
    float xh = fminf(fmaxf((p.x + 0.5f * nw) / ux, 0.0f), (float)MX);
    float yl = fminf(fmaxf((p.y - 0.5f * nh) / uy, 0.0f), (float)NY);
    float yh = fminf(fmaxf((p.y + 0.5f * nh) / uy, 0.0f), (float)NY);

    int bx0 = (int)floorf(xl);
    int by0 = (int)floorf(yl);

    float oxs[4], oys[4];
    int   ixs[4], iys[4];
#pragma unroll
    for (int d = 0; d < 4; d++) {
        int ix = bx0 + d;
        float fx = (float)ix;
        oxs[d] = fmaxf(fminf(xh, fx + 1.0f) - fmaxf(xl, fx), 0.0f);
        ixs[d] = min(max(ix, 0), MX - 1);
        int iy = by0 + d;
        float fy = (float)iy;
        oys[d] = fmaxf(fminf(yh, fy + 1.0f) - fmaxf(yl, fy), 0.0f);
        iys[d] = min(max(iy, 0), NY - 1);
    }

#pragma unroll
    for (int dx = 0; dx < 4; dx++) {
        if (oxs[dx] == 0.0f) continue;
        float wox = w * oxs[dx];
        int rowoff = ixs[dx] * NY;
#pragma unroll
        for (int dy = 0; dy < 4; dy++) {
            float v = wox * oys[dy];
            if (v != 0.0f) atomicAdd(&dm[rowoff + iys[dy]], v);
        }
    }
}

// ---------------------------------------------------------------------------
// Stage 1: U = dm @ C^T    (U[j][b] = sum_k dm[j][k] * C[b][k])
// 32x32 output tile per block, 256 threads (32x8), 4 outputs/thread.
// ---------------------------------------------------------------------------
__global__ __launch_bounds__(256)
void dct_y_kernel(const float* __restrict__ A,     // dm, 512x512
                  const float* __restrict__ B,     // C,  512x512
                  float* __restrict__ U) {
    __shared__ float As[32][33];
    __shared__ float Bs[32][33];
    int tx = threadIdx.x;            // 0..31
    int ty = threadIdx.y;            // 0..7
    int jb = blockIdx.y * 32;
    int bb = blockIdx.x * 32;
    float acc[4] = {0.f, 0.f, 0.f, 0.f};

    for (int k0 = 0; k0 < MX; k0 += 32) {
#pragma unroll
        for (int r = 0; r < 4; r++) {
            As[ty * 4 + r][tx] = A[(jb + ty * 4 + r) * NY + k0 + tx];
            Bs[ty * 4 + r][tx] = B[(bb + ty * 4 + r) * MX + k0 + tx];
        }
        __syncthreads();
#pragma unroll
        for (int k = 0; k < 32; k++) {
            float bv = Bs[tx][k];
#pragma unroll
            for (int r = 0; r < 4; r++) acc[r] += As[ty * 4 + r][k] * bv;
        }
        __syncthreads();
    }
#pragma unroll
    for (int r = 0; r < 4; r++)
        U[(jb + ty * 4 + r) * NY + bb + tx] = acc[r];
}

// ---------------------------------------------------------------------------
// Stage 2: T = C @ U  (T[a][b] = sum_j C[a][j] * U[j][b]), fused with the
// energy epilogue: e += wx[a]*wy[b]*pscale[a,b]*T^2; block-reduce; one
// atomicAdd per block of partial/(mx*ny).
// ---------------------------------------------------------------------------
__global__ __launch_bounds__(256)
void dct_x_energy_kernel(const float* __restrict__ Cm,   // 512x512
                         const float* __restrict__ U,    // 512x512
                         const float* __restrict__ unit_len,
                         float* __restrict__ out) {
    __shared__ float As[32][33];
    __shared__ float Bs[32][33];
    __shared__ float red[4];
    int tx = threadIdx.x;
    int ty = threadIdx.y;
    int a0 = blockIdx.y * 32;
    int b0 = blockIdx.x * 32;
    float acc[4] = {0.f, 0.f, 0.f, 0.f};

    for (int k0 = 0; k0 < MX; k0 += 32) {
#pragma unroll
        for (int r = 0; r < 4; r++) {
            As[ty * 4 + r][tx] = Cm[(a0 + ty * 4 + r) * MX + k0 + tx];
            Bs[ty * 4 + r][tx] = U[(k0 + ty * 4 + r) * NY + b0 + tx];
        }
        __syncthreads();
#pragma unroll
        for (int k = 0; k < 32; k++) {
            float bv = Bs[k][tx];
#pragma unroll
            for (int r = 0; r < 4; r++) acc[r] += As[ty * 4 + r][k] * bv;
        }
        __syncthreads();
    }

    // Energy epilogue.
    float ratio = unit_len[0] / unit_len[1];
    int b = b0 + tx;
    float wkb = (float)b * (TWO_PI / (float)NY) * ratio;
    float wyb = (b == 0) ? 1.0f : 2.0f;
    float e = 0.0f;
#pragma unroll
    for (int r = 0; r < 4; r++) {
        int a = a0 + ty * 4 + r;
        float wja = (float)a * (TWO_PI / (float)MX);
        float wsq = wja * wja + wkb * wkb;
        float ps = (a == 0 && b == 0) ? 0.0f : (1.0f / wsq);
        float wxa = (a == 0) ? 1.0f : 2.0f;
        e += wxa * wyb * ps * acc[r] * acc[r];
    }

    // Block reduction: wave64 shuffle, then LDS across the 4 waves.
    int lin = ty * 32 + tx;
#pragma unroll
    for (int off = 32; off > 0; off >>= 1) e += __shfl_down(e, off, 64);
    int lane = lin & 63;
    int wv = lin >> 6;
    if (lane == 0) red[wv] = e;
    __syncthreads();
    if (lin == 0) {
        float t = red[0] + red[1] + red[2] + red[3];
        atomicAdd(out, t * (1.0f / ((float)MX * (float)NY)));
    }
}

extern "C" void kernel_launch(void* const* d_in, const int* in_sizes, int n_in,
                              void* d_out, int out_size, void* d_ws, size_t ws_size,
                              hipStream_t stream) {
    const float2* node_pos  = (const float2*)d_in[0];
    const float2* node_size = (const float2*)d_in[1];
    const float*  node_wt   = (const float*)d_in[2];
    const float*  exp_ratio = (const float*)d_in[3];
    const float*  unit_len  = (const float*)d_in[4];
    const float*  init_dm   = (const float*)d_in[5];
    float* out = (float*)d_out;
    int n = in_sizes[2];   // node_weight element count = NUM_NODES

    float* ws   = (float*)d_ws;
    float* dm   = ws;                       // 512*512
    float* Cmat = ws + MX * NY;             // 512*512
    float* U    = ws + 2 * MX * NY;         // 512*512

    // dm = init_density_map (workspace is poisoned; must init).
    hipMemcpyAsync(dm, init_dm, (size_t)MX * NY * sizeof(float),
                   hipMemcpyDeviceToDevice, stream);
    // out = 0 (accumulated via atomicAdd).
    hipMemsetAsync(d_out, 0, sizeof(float), stream);

    gen_cos_kernel<<<(MX * NY) / 256, 256, 0, stream>>>(Cmat);

    scatter_kernel<<<(n + 255) / 256, 256, 0, stream>>>(
        node_pos, node_size, node_wt, exp_ratio, unit_len, dm, n);

    dim3 blk(32, 8);
    dim3 grd(NY / 32, MX / 32);
    dct_y_kernel<<<grd, blk, 0, stream>>>(dm, Cmat, U);
    dct_x_energy_kernel<<<grd, blk, 0, stream>>>(Cmat, U, unit_len, out);
}

// Round 2
// 342.282 us; speedup vs baseline: 2.6547x; 2.6547x over previous
//
#include <hip/hip_runtime.h>
#include <math.h>

#define MX 512
#define NY 512
#define TWO_PI 6.283185307179586f

// Tiling for the scatter binning pipeline: 16x16 bins per tile, 32x32 tiles.
#define TILE_SHIFT 4
#define TILES_SIDE 32
#define NTILES 1024          // TILES_SIDE^2
#define NPB 8192             // nodes per block in count/place kernels
#define LOCAL_DIM 20         // 16 + 3 halo + 1 spare

// ---------------------------------------------------------------------------
// Footprint math shared by all scatter kernels. MUST be bit-identical
// everywhere so tile assignment (K1) and accumulation (K4) agree.
// ---------------------------------------------------------------------------
__device__ __forceinline__ void node_bounds(float2 p, float2 s, float ux, float uy,
                                            float& xl, float& xh, float& yl, float& yh,
                                            float& nw, float& nh) {
    const float SQ2 = 1.41421356237309515f;
    nw = fmaxf(s.x, SQ2 * ux);
    nh = fmaxf(s.y, SQ2 * uy);
    xl = fminf(fmaxf((p.x - 0.5f * nw) / ux, 0.0f), (float)MX);
    xh = fminf(fmaxf((p.x + 0.5f * nw) / ux, 0.0f), (float)MX);
    yl = fminf(fmaxf((p.y - 0.5f * nh) / uy, 0.0f), (float)NY);
    yh = fminf(fmaxf((p.y + 0.5f * nh) / uy, 0.0f), (float)NY);
}

// ---------------------------------------------------------------------------
// K1: count nodes per tile; cache tile id per node.
// ---------------------------------------------------------------------------
__global__ __launch_bounds__(256)
void count_kernel(const float2* __restrict__ pos, const float2* __restrict__ size,
                  const float* __restrict__ unit_len,
                  unsigned short* __restrict__ tile16,
                  unsigned int* __restrict__ cnt, int n) {
    __shared__ unsigned int h[NTILES];
    for (int t = threadIdx.x; t < NTILES; t += 256) h[t] = 0;
    __syncthreads();

    float ux = unit_len[0], uy = unit_len[1];
    int start = blockIdx.x * NPB;
    int end = min(start + NPB, n);
    for (int i = start + (int)threadIdx.x; i < end; i += 256) {
        float xl, xh, yl, yh, nw, nh;
        node_bounds(pos[i], size[i], ux, uy, xl, xh, yl, yh, nw, nh);
        int bx0 = min((int)floorf(xl), MX - 1);
        int by0 = min((int)floorf(yl), NY - 1);
        int t = ((bx0 >> TILE_SHIFT) << 5) | (by0 >> TILE_SHIFT);
        tile16[i] = (unsigned short)t;
        atomicAdd(&h[t], 1u);
    }
    __syncthreads();
    for (int t = threadIdx.x; t < NTILES; t += 256) {
        unsigned int c = h[t];
        if (c) atomicAdd(&cnt[t], c);
    }
}

// ---------------------------------------------------------------------------
// K2: exclusive prefix sum over 1024 tile counts (single block).
// ---------------------------------------------------------------------------
__global__ __launch_bounds__(256)
void scan_kernel(const unsigned int* __restrict__ cnt,
                 unsigned int* __restrict__ base,
                 unsigned int* __restrict__ cursor) {
    __shared__ unsigned int s[256];
    int tid = threadIdx.x;
    unsigned int loc[4];
    unsigned int sum = 0;
#pragma unroll
    for (int k = 0; k < 4; k++) { loc[k] = cnt[tid * 4 + k]; sum += loc[k]; }
    s[tid] = sum;
    __syncthreads();
    for (int off = 1; off < 256; off <<= 1) {
        unsigned int v = (tid >= off) ? s[tid - off] : 0u;
        __syncthreads();
        s[tid] += v;
        __syncthreads();
    }
    unsigned int ex = (tid == 0) ? 0u : s[tid - 1];
#pragma unroll
    for (int k = 0; k < 4; k++) {
        base[tid * 4 + k] = ex;
        cursor[tid * 4 + k] = ex;
        ex += loc[k];
    }
}

// ---------------------------------------------------------------------------
// K3: place node indices into per-tile segments.
// ---------------------------------------------------------------------------
__global__ __launch_bounds__(256)
void place_kernel(const unsigned short* __restrict__ tile16,
                  unsigned int* __restrict__ cursor,
                  unsigned int* __restrict__ sorted, int n) {
    __shared__ unsigned int h[NTILES];
    __shared__ unsigned int bb[NTILES];
    for (int t = threadIdx.x; t < NTILES; t += 256) h[t] = 0;
    __syncthreads();

    int start = blockIdx.x * NPB;
    int end = min(start + NPB, n);
    unsigned int myoff[NPB / 256];
    unsigned int myt[NPB / 256];
#pragma unroll
    for (int k = 0; k < NPB / 256; k++) {
        int i = start + k * 256 + (int)threadIdx.x;
        if (i < end) {
            unsigned int t = tile16[i];
            myt[k] = t;
            myoff[k] = atomicAdd(&h[t], 1u);
        }
    }
    __syncthreads();
    for (int t = threadIdx.x; t < NTILES; t += 256) {
        unsigned int c = h[t];
        if (c) bb[t] = atomicAdd(&cursor[t], c);
    }
    __syncthreads();
#pragma unroll
    for (int k = 0; k < NPB / 256; k++) {
        int i = start + k * 256 + (int)threadIdx.x;
        if (i < end) sorted[bb[myt[k]] + myoff[k]] = (unsigned int)i;
    }
}

// ---------------------------------------------------------------------------
// K4: one workgroup per tile — accumulate footprints in LDS, merge once.
// ---------------------------------------------------------------------------
__global__ __launch_bounds__(256)
void accum_kernel(const unsigned int* __restrict__ sorted,
                  const unsigned int* __restrict__ base,
                  const unsigned int* __restrict__ cnt,
                  const float2* __restrict__ pos, const float2* __restrict__ size,
                  const float* __restrict__ nwt, const float* __restrict__ er,
                  const float* __restrict__ unit_len,
                  float* __restrict__ dm) {
    __shared__ float acc[LOCAL_DIM][LOCAL_DIM + 1];
    int t = blockIdx.x;
    int tbx = (t >> 5) << TILE_SHIFT;    // bin base x of this tile
    int tby = (t & 31) << TILE_SHIFT;    // bin base y

    for (int e = threadIdx.x; e < LOCAL_DIM * LOCAL_DIM; e += 256)
        acc[e / LOCAL_DIM][e % LOCAL_DIM] = 0.0f;
    __syncthreads();

    unsigned int b0 = base[t];
    unsigned int c = cnt[t];
    float ux = unit_len[0], uy = unit_len[1];

    for (unsigned int k = threadIdx.x; k < c; k += 256) {
        int i = (int)sorted[b0 + k];
        float2 p = pos[i];
        float2 s = size[i];
        float xl, xh, yl, yh, nw, nh;
        node_bounds(p, s, ux, uy, xl, xh, yl, yh, nw, nh);
        float w = nwt[i] * er[i] * (s.x * s.y) / (nw * nh);
        int bx0 = min((int)floorf(xl), MX - 1);
        int by0 = min((int)floorf(yl), NY - 1);

        float oxs[4], oys[4];
        int lxs[4], lys[4];
#pragma unroll
        for (int d = 0; d < 4; d++) {
            int ix = bx0 + d;
            float fx = (float)ix;
            oxs[d] = fmaxf(fminf(xh, fx + 1.0f) - fmaxf(xl, fx), 0.0f);
            lxs[d] = min(max(min(ix, MX - 1) - tbx, 0), LOCAL_DIM - 1);
            int iy = by0 + d;
            float fy = (float)iy;
            oys[d] = fmaxf(fminf(yh, fy + 1.0f) - fmaxf(yl, fy), 0.0f);
            lys[d] = min(max(min(iy, NY - 1) - tby, 0), LOCAL_DIM - 1);
        }
#pragma unroll
        for (int dx = 0; dx < 4; dx++) {
            if (oxs[dx] == 0.0f) continue;
            float wox = w * oxs[dx];
#pragma unroll
            for (int dy = 0; dy < 4; dy++) {
                float v = wox * oys[dy];
                if (v != 0.0f) atomicAdd(&acc[lxs[dx]][lys[dy]], v);
            }
        }
    }
    __syncthreads();

    for (int e = threadIdx.x; e < LOCAL_DIM * LOCAL_DIM; e += 256) {
        int lx = e / LOCAL_DIM, ly = e % LOCAL_DIM;
        float v = acc[lx][ly];
        int gx = tbx + lx, gy = tby + ly;
        if (v != 0.0f && gx < MX && gy < NY)
            atomicAdd(&dm[gx * NY + gy], v);
    }
}

// ---------------------------------------------------------------------------
// Fallback: direct-atomic scatter (used when ws is too small for binning).
// ---------------------------------------------------------------------------
__global__ __launch_bounds__(256)
void scatter_kernel(const float2* __restrict__ pos,
                    const float2* __restrict__ size,
                    const float* __restrict__ nwt,
                    const float* __restrict__ er,
                    const float* __restrict__ unit_len,
                    float* __restrict__ dm, int n) {
    int i = blockIdx.x * blockDim.x + threadIdx.x;
    if (i >= n) return;
    float ux = unit_len[0], uy = unit_len[1];
    float2 p = pos[i];
    float2 s = size[i];
    float xl, xh, yl, yh, nw, nh;
    node_bounds(p, s, ux, uy, xl, xh, yl, yh, nw, nh);
    float w = nwt[i] * er[i] * (s.x * s.y) / (nw * nh);
    int bx0 = (int)floorf(xl);
    int by0 = (int)floorf(yl);
    float oxs[4], oys[4];
    int ixs[4], iys[4];
#pragma unroll
    for (int d = 0; d < 4; d++) {
        int ix = bx0 + d;
        float fx = (float)ix;
        oxs[d] = fmaxf(fminf(xh, fx + 1.0f) - fmaxf(xl, fx), 0.0f);
        ixs[d] = min(max(ix, 0), MX - 1);
        int iy = by0 + d;
        float fy = (float)iy;
        oys[d] = fmaxf(fminf(yh, fy + 1.0f) - fmaxf(yl, fy), 0.0f);
        iys[d] = min(max(iy, 0), NY - 1);
    }
#pragma unroll
    for (int dx = 0; dx < 4; dx++) {
        if (oxs[dx] == 0.0f) continue;
        float wox = w * oxs[dx];
        int rowoff = ixs[dx] * NY;
#pragma unroll
        for (int dy = 0; dy < 4; dy++) {
            float v = wox * oys[dy];
            if (v != 0.0f) atomicAdd(&dm[rowoff + iys[dy]], v);
        }
    }
}

// ---------------------------------------------------------------------------
// DCT cos matrix: C[a][j] = cos(pi * a * (2j+1) / 1024).
// ---------------------------------------------------------------------------
__global__ void gen_cos_kernel(float* __restrict__ C) {
    int idx = blockIdx.x * blockDim.x + threadIdx.x;
    int a = idx >> 9;
    int j = idx & 511;
    float x = (float)(a * (2 * j + 1)) * (1.0f / 1024.0f);
    C[idx] = cospif(x);
}

// ---------------------------------------------------------------------------
// Stage 1: U = dm @ C^T
// ---------------------------------------------------------------------------
__global__ __launch_bounds__(256)
void dct_y_kernel(const float* __restrict__ A, const float* __restrict__ B,
                  float* __restrict__ U) {
    __shared__ float As[32][33];
    __shared__ float Bs[32][33];
    int tx = threadIdx.x;
    int ty = threadIdx.y;
    int jb = blockIdx.y * 32;
    int bb = blockIdx.x * 32;
    float acc[4] = {0.f, 0.f, 0.f, 0.f};
    for (int k0 = 0; k0 < MX; k0 += 32) {
#pragma unroll
        for (int r = 0; r < 4; r++) {
            As[ty * 4 + r][tx] = A[(jb + ty * 4 + r) * NY + k0 + tx];
            Bs[ty * 4 + r][tx] = B[(bb + ty * 4 + r) * MX + k0 + tx];
        }
        __syncthreads();
#pragma unroll
        for (int k = 0; k < 32; k++) {
            float bv = Bs[tx][k];
#pragma unroll
            for (int r = 0; r < 4; r++) acc[r] += As[ty * 4 + r][k] * bv;
        }
        __syncthreads();
    }
#pragma unroll
    for (int r = 0; r < 4; r++)
        U[(jb + ty * 4 + r) * NY + bb + tx] = acc[r];
}

// ---------------------------------------------------------------------------
// Stage 2: T = C @ U fused with energy reduction.
// ---------------------------------------------------------------------------
__global__ __launch_bounds__(256)
void dct_x_energy_kernel(const float* __restrict__ Cm, const float* __restrict__ U,
                         const float* __restrict__ unit_len,
                         float* __restrict__ out) {
    __shared__ float As[32][33];
    __shared__ float Bs[32][33];
    __shared__ float red[4];
    int tx = threadIdx.x;
    int ty = threadIdx.y;
    int a0 = blockIdx.y * 32;
    int b0 = blockIdx.x * 32;
    float acc[4] = {0.f, 0.f, 0.f, 0.f};
    for (int k0 = 0; k0 < MX; k0 += 32) {
#pragma unroll
        for (int r = 0; r < 4; r++) {
            As[ty * 4 + r][tx] = Cm[(a0 + ty * 4 + r) * MX + k0 + tx];
            Bs[ty * 4 + r][tx] = U[(k0 + ty * 4 + r) * NY + b0 + tx];
        }
        __syncthreads();
#pragma unroll
        for (int k = 0; k < 32; k++) {
            float bv = Bs[k][tx];
#pragma unroll
            for (int r = 0; r < 4; r++) acc[r] += As[ty * 4 + r][k] * bv;
        }
        __syncthreads();
    }
    float ratio = unit_len[0] / unit_len[1];
    int b = b0 + tx;
    float wkb = (float)b * (TWO_PI / (float)NY) * ratio;
    float wyb = (b == 0) ? 1.0f : 2.0f;
    float e = 0.0f;
#pragma unroll
    for (int r = 0; r < 4; r++) {
        int a = a0 + ty * 4 + r;
        float wja = (float)a * (TWO_PI / (float)MX);
        float wsq = wja * wja + wkb * wkb;
        float ps = (a == 0 && b == 0) ? 0.0f : (1.0f / wsq);
        float wxa = (a == 0) ? 1.0f : 2.0f;
        e += wxa * wyb * ps * acc[r] * acc[r];
    }
    int lin = ty * 32 + tx;
#pragma unroll
    for (int off = 32; off > 0; off >>= 1) e += __shfl_down(e, off, 64);
    int lane = lin & 63;
    int wv = lin >> 6;
    if (lane == 0) red[wv] = e;
    __syncthreads();
    if (lin == 0) {
        float tsum = red[0] + red[1] + red[2] + red[3];
        atomicAdd(out, tsum * (1.0f / ((float)MX * (float)NY)));
    }
}

extern "C" void kernel_launch(void* const* d_in, const int* in_sizes, int n_in,
                              void* d_out, int out_size, void* d_ws, size_t ws_size,
                              hipStream_t stream) {
    const float2* node_pos  = (const float2*)d_in[0];
    const float2* node_size = (const float2*)d_in[1];
    const float*  node_wt   = (const float*)d_in[2];
    const float*  exp_ratio = (const float*)d_in[3];
    const float*  unit_len  = (const float*)d_in[4];
    const float*  init_dm   = (const float*)d_in[5];
    float* out = (float*)d_out;
    int n = in_sizes[2];

    char* wsb = (char*)d_ws;
    size_t off = 0;
    auto alloc = [&](size_t bytes) { void* p = wsb + off; off = (off + bytes + 255) & ~(size_t)255; return p; };
    float*          dm     = (float*)alloc((size_t)MX * NY * sizeof(float));
    float*          Cmat   = (float*)alloc((size_t)MX * NY * sizeof(float));
    float*          U      = (float*)alloc((size_t)MX * NY * sizeof(float));
    unsigned int*   cnt    = (unsigned int*)alloc(NTILES * sizeof(unsigned int));
    unsigned int*   tbase  = (unsigned int*)alloc(NTILES * sizeof(unsigned int));
    unsigned int*   cursor = (unsigned int*)alloc(NTILES * sizeof(unsigned int));
    unsigned short* tile16 = (unsigned short*)alloc((size_t)n * sizeof(unsigned short));
    unsigned int*   sorted = (unsigned int*)alloc((size_t)n * sizeof(unsigned int));
    bool use_binned = (off <= ws_size);

    hipMemcpyAsync(dm, init_dm, (size_t)MX * NY * sizeof(float),
                   hipMemcpyDeviceToDevice, stream);
    hipMemsetAsync(d_out, 0, sizeof(float), stream);

    gen_cos_kernel<<<(MX * NY) / 256, 256, 0, stream>>>(Cmat);

    if (use_binned) {
        hipMemsetAsync(cnt, 0, NTILES * sizeof(unsigned int), stream);
        int nblk = (n + NPB - 1) / NPB;
        count_kernel<<<nblk, 256, 0, stream>>>(node_pos, node_size, unit_len,
                                               tile16, cnt, n);
        scan_kernel<<<1, 256, 0, stream>>>(cnt, tbase, cursor);
        place_kernel<<<nblk, 256, 0, stream>>>(tile16, cursor, sorted, n);
        accum_kernel<<<NTILES, 256, 0, stream>>>(sorted, tbase, cnt,
                                                 node_pos, node_size,
                                                 node_wt, exp_ratio, unit_len, dm);
    } else {
        scatter_kernel<<<(n + 255) / 256, 256, 0, stream>>>(
            node_pos, node_size, node_wt, exp_ratio, unit_len, dm, n);
    }

    dim3 blk(32, 8);
    dim3 grd(NY / 32, MX / 32);
    dct_y_kernel<<<grd, blk, 0, stream>>>(dm, Cmat, U);
    dct_x_energy_kernel<<<grd, blk, 0, stream>>>(Cmat, U, unit_len, out);
}

// Round 3
// 303.420 us; speedup vs baseline: 2.9947x; 1.1281x over previous
//
#include <hip/hip_runtime.h>
#include <math.h>

#define MX 512
#define NY 512
#define TWO_PI 6.283185307179586f

#define TILE_SHIFT 4
#define TILES_SIDE 32
#define NTILES 1024
#define NPB 8192
#define LOCAL_DIM 20

typedef __attribute__((ext_vector_type(8))) short short8;
typedef __attribute__((ext_vector_type(4))) float float4_t;

// ---------------------------------------------------------------------------
// bf16 helpers (round-to-nearest-even via bias trick).
// ---------------------------------------------------------------------------
__device__ __forceinline__ unsigned short f2bf(float x) {
    union { float f; unsigned u; } v; v.f = x;
    unsigned r = v.u + 0x7fffu + ((v.u >> 16) & 1u);
    return (unsigned short)(r >> 16);
}
__device__ __forceinline__ float bf2f(unsigned short h) {
    union { float f; unsigned u; } v; v.u = ((unsigned)h) << 16;
    return v.f;
}

// ---------------------------------------------------------------------------
// Shared footprint math (must be identical across kernels).
// ---------------------------------------------------------------------------
__device__ __forceinline__ void node_bounds(float2 p, float2 s, float ux, float uy,
                                            float& xl, float& xh, float& yl, float& yh,
                                            float& nw, float& nh) {
    const float SQ2 = 1.41421356237309515f;
    nw = fmaxf(s.x, SQ2 * ux);
    nh = fmaxf(s.y, SQ2 * uy);
    xl = fminf(fmaxf((p.x - 0.5f * nw) / ux, 0.0f), (float)MX);
    xh = fminf(fmaxf((p.x + 0.5f * nw) / ux, 0.0f), (float)MX);
    yl = fminf(fmaxf((p.y - 0.5f * nh) / uy, 0.0f), (float)NY);
    yh = fminf(fmaxf((p.y + 0.5f * nh) / uy, 0.0f), (float)NY);
}

// ---------------------------------------------------------------------------
// K1: count nodes per tile.
// ---------------------------------------------------------------------------
__global__ __launch_bounds__(256)
void count_kernel(const float2* __restrict__ pos, const float2* __restrict__ size,
                  const float* __restrict__ unit_len,
                  unsigned int* __restrict__ cnt, int n) {
    __shared__ unsigned int h[NTILES];
    for (int t = threadIdx.x; t < NTILES; t += 256) h[t] = 0;
    __syncthreads();
    float ux = unit_len[0], uy = unit_len[1];
    int start = blockIdx.x * NPB;
    int end = min(start + NPB, n);
    for (int i = start + (int)threadIdx.x; i < end; i += 256) {
        float xl, xh, yl, yh, nw, nh;
        node_bounds(pos[i], size[i], ux, uy, xl, xh, yl, yh, nw, nh);
        int bx0 = min((int)floorf(xl), MX - 1);
        int by0 = min((int)floorf(yl), NY - 1);
        int t = ((bx0 >> TILE_SHIFT) << 5) | (by0 >> TILE_SHIFT);
        atomicAdd(&h[t], 1u);
    }
    __syncthreads();
    for (int t = threadIdx.x; t < NTILES; t += 256) {
        unsigned int c = h[t];
        if (c) atomicAdd(&cnt[t], c);
    }
}

// ---------------------------------------------------------------------------
// K2: exclusive scan over 1024 counts.
// ---------------------------------------------------------------------------
__global__ __launch_bounds__(256)
void scan_kernel(const unsigned int* __restrict__ cnt,
                 unsigned int* __restrict__ base,
                 unsigned int* __restrict__ cursor) {
    __shared__ unsigned int s[256];
    int tid = threadIdx.x;
    unsigned int loc[4];
    unsigned int sum = 0;
#pragma unroll
    for (int k = 0; k < 4; k++) { loc[k] = cnt[tid * 4 + k]; sum += loc[k]; }
    s[tid] = sum;
    __syncthreads();
    for (int off = 1; off < 256; off <<= 1) {
        unsigned int v = (tid >= off) ? s[tid - off] : 0u;
        __syncthreads();
        s[tid] += v;
        __syncthreads();
    }
    unsigned int ex = (tid == 0) ? 0u : s[tid - 1];
#pragma unroll
    for (int k = 0; k < 4; k++) {
        base[tid * 4 + k] = ex;
        cursor[tid * 4 + k] = ex;
        ex += loc[k];
    }
}

// ---------------------------------------------------------------------------
// K3-A: payload place — sequential node reads, scatter (bounds,w) payload
// into per-tile segments. K4 then streams sequentially (no gather).
// ---------------------------------------------------------------------------
__global__ __launch_bounds__(256)
void place_payload_kernel(const float2* __restrict__ pos, const float2* __restrict__ size,
                          const float* __restrict__ nwt, const float* __restrict__ er,
                          const float* __restrict__ unit_len,
                          unsigned int* __restrict__ cursor,
                          float4* __restrict__ pb, float* __restrict__ pw, int n) {
    __shared__ unsigned int h[NTILES];
    __shared__ unsigned int bb[NTILES];
    for (int t = threadIdx.x; t < NTILES; t += 256) h[t] = 0;
    __syncthreads();
    float ux = unit_len[0], uy = unit_len[1];
    int start = blockIdx.x * NPB;
    int end = min(start + NPB, n);
    unsigned int packed[NPB / 256];
#pragma unroll
    for (int k = 0; k < NPB / 256; k++) {
        int i = start + k * 256 + (int)threadIdx.x;
        if (i < end) {
            float xl, xh, yl, yh, nw, nh;
            node_bounds(pos[i], size[i], ux, uy, xl, xh, yl, yh, nw, nh);
            int bx0 = min((int)floorf(xl), MX - 1);
            int by0 = min((int)floorf(yl), NY - 1);
            unsigned int t = ((bx0 >> TILE_SHIFT) << 5) | (by0 >> TILE_SHIFT);
            packed[k] = (t << 13) | atomicAdd(&h[t], 1u);
        }
    }
    __syncthreads();
    for (int t = threadIdx.x; t < NTILES; t += 256) {
        unsigned int c = h[t];
        if (c) bb[t] = atomicAdd(&cursor[t], c);
    }
    __syncthreads();
#pragma unroll
    for (int k = 0; k < NPB / 256; k++) {
        int i = start + k * 256 + (int)threadIdx.x;
        if (i < end) {
            float2 p = pos[i], s = size[i];
            float xl, xh, yl, yh, nw, nh;
            node_bounds(p, s, ux, uy, xl, xh, yl, yh, nw, nh);
            float w = nwt[i] * er[i] * (s.x * s.y) / (nw * nh);
            unsigned int t = packed[k] >> 13;
            unsigned int o = packed[k] & 8191u;
            unsigned int dst = bb[t] + o;
            pb[dst] = make_float4(xl, xh, yl, yh);
            pw[dst] = w;
        }
    }
}

// ---------------------------------------------------------------------------
// K4-A: accumulate payload segments (sequential reads) into LDS tile, merge.
// ---------------------------------------------------------------------------
__global__ __launch_bounds__(256)
void accum_payload_kernel(const float4* __restrict__ pb, const float* __restrict__ pw,
                          const unsigned int* __restrict__ base,
                          const unsigned int* __restrict__ cnt,
                          float* __restrict__ dm) {
    __shared__ float acc[LOCAL_DIM][LOCAL_DIM + 1];
    int t = blockIdx.x;
    int tbx = (t >> 5) << TILE_SHIFT;
    int tby = (t & 31) << TILE_SHIFT;
    for (int e = threadIdx.x; e < LOCAL_DIM * LOCAL_DIM; e += 256)
        acc[e / LOCAL_DIM][e % LOCAL_DIM] = 0.0f;
    __syncthreads();

    unsigned int b0 = base[t];
    unsigned int c = cnt[t];
    for (unsigned int k = threadIdx.x; k < c; k += 256) {
        float4 b4 = pb[b0 + k];
        float w = pw[b0 + k];
        float xl = b4.x, xh = b4.y, yl = b4.z, yh = b4.w;
        int bx0 = min((int)floorf(xl), MX - 1);
        int by0 = min((int)floorf(yl), NY - 1);
        float oxs[4], oys[4];
        int lxs[4], lys[4];
#pragma unroll
        for (int d = 0; d < 4; d++) {
            int ix = bx0 + d;
            float fx = (float)ix;
            oxs[d] = fmaxf(fminf(xh, fx + 1.0f) - fmaxf(xl, fx), 0.0f);
            lxs[d] = min(max(min(ix, MX - 1) - tbx, 0), LOCAL_DIM - 1);
            int iy = by0 + d;
            float fy = (float)iy;
            oys[d] = fmaxf(fminf(yh, fy + 1.0f) - fmaxf(yl, fy), 0.0f);
            lys[d] = min(max(min(iy, NY - 1) - tby, 0), LOCAL_DIM - 1);
        }
#pragma unroll
        for (int dx = 0; dx < 4; dx++) {
            if (oxs[dx] == 0.0f) continue;
            float wox = w * oxs[dx];
#pragma unroll
            for (int dy = 0; dy < 4; dy++) {
                float v = wox * oys[dy];
                if (v != 0.0f) atomicAdd(&acc[lxs[dx]][lys[dy]], v);
            }
        }
    }
    __syncthreads();
    for (int e = threadIdx.x; e < LOCAL_DIM * LOCAL_DIM; e += 256) {
        int lx = e / LOCAL_DIM, ly = e % LOCAL_DIM;
        float v = acc[lx][ly];
        int gx = tbx + lx, gy = tby + ly;
        if (v != 0.0f && gx < MX && gy < NY)
            atomicAdd(&dm[gx * NY + gy], v);
    }
}

// ---------------------------------------------------------------------------
// Tier-B fallback (index sort, gather accumulate) — round-2 proven path.
// ---------------------------------------------------------------------------
__global__ __launch_bounds__(256)
void place_index_kernel(const float2* __restrict__ pos, const float2* __restrict__ size,
                        const float* __restrict__ unit_len,
                        unsigned int* __restrict__ cursor,
                        unsigned int* __restrict__ sorted, int n) {
    __shared__ unsigned int h[NTILES];
    __shared__ unsigned int bb[NTILES];
    for (int t = threadIdx.x; t < NTILES; t += 256) h[t] = 0;
    __syncthreads();
    float ux = unit_len[0], uy = unit_len[1];
    int start = blockIdx.x * NPB;
    int end = min(start + NPB, n);
    unsigned int packed[NPB / 256];
#pragma unroll
    for (int k = 0; k < NPB / 256; k++) {
        int i = start + k * 256 + (int)threadIdx.x;
        if (i < end) {
            float xl, xh, yl, yh, nw, nh;
            node_bounds(pos[i], size[i], ux, uy, xl, xh, yl, yh, nw, nh);
            int bx0 = min((int)floorf(xl), MX - 1);
            int by0 = min((int)floorf(yl), NY - 1);
            unsigned int t = ((bx0 >> TILE_SHIFT) << 5) | (by0 >> TILE_SHIFT);
            packed[k] = (t << 13) | atomicAdd(&h[t], 1u);
        }
    }
    __syncthreads();
    for (int t = threadIdx.x; t < NTILES; t += 256) {
        unsigned int c = h[t];
        if (c) bb[t] = atomicAdd(&cursor[t], c);
    }
    __syncthreads();
#pragma unroll
    for (int k = 0; k < NPB / 256; k++) {
        int i = start + k * 256 + (int)threadIdx.x;
        if (i < end) {
            unsigned int t = packed[k] >> 13;
            sorted[bb[t] + (packed[k] & 8191u)] = (unsigned int)i;
        }
    }
}

__global__ __launch_bounds__(256)
void accum_index_kernel(const unsigned int* __restrict__ sorted,
                        const unsigned int* __restrict__ base,
                        const unsigned int* __restrict__ cnt,
                        const float2* __restrict__ pos, const float2* __restrict__ size,
                        const float* __restrict__ nwt, const float* __restrict__ er,
                        const float* __restrict__ unit_len,
                        float* __restrict__ dm) {
    __shared__ float acc[LOCAL_DIM][LOCAL_DIM + 1];
    int t = blockIdx.x;
    int tbx = (t >> 5) << TILE_SHIFT;
    int tby = (t & 31) << TILE_SHIFT;
    for (int e = threadIdx.x; e < LOCAL_DIM * LOCAL_DIM; e += 256)
        acc[e / LOCAL_DIM][e % LOCAL_DIM] = 0.0f;
    __syncthreads();
    unsigned int b0 = base[t];
    unsigned int c = cnt[t];
    float ux = unit_len[0], uy = unit_len[1];
    for (unsigned int k = threadIdx.x; k < c; k += 256) {
        int i = (int)sorted[b0 + k];
        float2 p = pos[i], s = size[i];
        float xl, xh, yl, yh, nw, nh;
        node_bounds(p, s, ux, uy, xl, xh, yl, yh, nw, nh);
        float w = nwt[i] * er[i] * (s.x * s.y) / (nw * nh);
        int bx0 = min((int)floorf(xl), MX - 1);
        int by0 = min((int)floorf(yl), NY - 1);
        float oxs[4], oys[4];
        int lxs[4], lys[4];
#pragma unroll
        for (int d = 0; d < 4; d++) {
            int ix = bx0 + d;
            float fx = (float)ix;
            oxs[d] = fmaxf(fminf(xh, fx + 1.0f) - fmaxf(xl, fx), 0.0f);
            lxs[d] = min(max(min(ix, MX - 1) - tbx, 0), LOCAL_DIM - 1);
            int iy = by0 + d;
            float fy = (float)iy;
            oys[d] = fmaxf(fminf(yh, fy + 1.0f) - fmaxf(yl, fy), 0.0f);
            lys[d] = min(max(min(iy, NY - 1) - tby, 0), LOCAL_DIM - 1);
        }
#pragma unroll
        for (int dx = 0; dx < 4; dx++) {
            if (oxs[dx] == 0.0f) continue;
            float wox = w * oxs[dx];
#pragma unroll
            for (int dy = 0; dy < 4; dy++) {
                float v = wox * oys[dy];
                if (v != 0.0f) atomicAdd(&acc[lxs[dx]][lys[dy]], v);
            }
        }
    }
    __syncthreads();
    for (int e = threadIdx.x; e < LOCAL_DIM * LOCAL_DIM; e += 256) {
        int lx = e / LOCAL_DIM, ly = e % LOCAL_DIM;
        float v = acc[lx][ly];
        int gx = tbx + lx, gy = tby + ly;
        if (v != 0.0f && gx < MX && gy < NY)
            atomicAdd(&dm[gx * NY + gy], v);
    }
}

// ---------------------------------------------------------------------------
// Tier-C fallback: direct global-atomic scatter.
// ---------------------------------------------------------------------------
__global__ __launch_bounds__(256)
void scatter_kernel(const float2* __restrict__ pos, const float2* __restrict__ size,
                    const float* __restrict__ nwt, const float* __restrict__ er,
                    const float* __restrict__ unit_len,
                    float* __restrict__ dm, int n) {
    int i = blockIdx.x * blockDim.x + threadIdx.x;
    if (i >= n) return;
    float ux = unit_len[0], uy = unit_len[1];
    float2 p = pos[i], s = size[i];
    float xl, xh, yl, yh, nw, nh;
    node_bounds(p, s, ux, uy, xl, xh, yl, yh, nw, nh);
    float w = nwt[i] * er[i] * (s.x * s.y) / (nw * nh);
    int bx0 = (int)floorf(xl);
    int by0 = (int)floorf(yl);
#pragma unroll
    for (int dx = 0; dx < 4; dx++) {
        int ix = bx0 + dx;
        float fx = (float)ix;
        float ox = fmaxf(fminf(xh, fx + 1.0f) - fmaxf(xl, fx), 0.0f);
        if (ox == 0.0f) continue;
        int rowoff = min(max(ix, 0), MX - 1) * NY;
        float wox = w * ox;
#pragma unroll
        for (int dy = 0; dy < 4; dy++) {
            int iy = by0 + dy;
            float fy = (float)iy;
            float oy = fmaxf(fminf(yh, fy + 1.0f) - fmaxf(yl, fy), 0.0f);
            float v = wox * oy;
            if (v != 0.0f) atomicAdd(&dm[rowoff + min(max(iy, 0), NY - 1)], v);
        }
    }
}

// ---------------------------------------------------------------------------
// Cos matrix in bf16 hi/lo: C[a][j] = cos(pi a (2j+1)/1024).
// ---------------------------------------------------------------------------
__global__ void gen_cos_kernel(unsigned short* __restrict__ Ch,
                               unsigned short* __restrict__ Cl) {
    int idx = blockIdx.x * blockDim.x + threadIdx.x;
    int a = idx >> 9;
    int j = idx & 511;
    float x = cospif((float)(a * (2 * j + 1)) * (1.0f / 1024.0f));
    unsigned short hi = f2bf(x);
    Ch[idx] = hi;
    Cl[idx] = f2bf(x - bf2f(hi));
}

// dm (fp32) -> bf16 hi/lo
__global__ void cvt_dm_kernel(const float* __restrict__ dm,
                              unsigned short* __restrict__ dmh,
                              unsigned short* __restrict__ dml) {
    int idx = blockIdx.x * blockDim.x + threadIdx.x;
    float x = dm[idx];
    unsigned short hi = f2bf(x);
    dmh[idx] = hi;
    dml[idx] = f2bf(x - bf2f(hi));
}

// ---------------------------------------------------------------------------
// Stage 1 (MFMA): U[j][b] = sum_k dm[j][k] * C[b][k]; store U^T in bf16 hi/lo.
// A-frag: A[m=lane&15][k=q*8+jj] from dm row (jt+m).
// B-frag: B[k][n=lane&15] = C[bt+n][k] from C row (bt+n) — contiguous.
// C/D: row = q*4+r, col = lane&15.
// ---------------------------------------------------------------------------
__global__ __launch_bounds__(256)
void dct1_mfma_kernel(const unsigned short* __restrict__ dmh,
                      const unsigned short* __restrict__ dml,
                      const unsigned short* __restrict__ Ch,
                      const unsigned short* __restrict__ Cl,
                      unsigned short* __restrict__ UhT,
                      unsigned short* __restrict__ UlT) {
    int lane = threadIdx.x & 63;
    int wv = threadIdx.x >> 6;
    int tile = blockIdx.x * 4 + wv;          // 1024 tiles of 16x16
    int jt = (tile >> 5) * 16;
    int bt = (tile & 31) * 16;
    int m = lane & 15, q = lane >> 4;
    float4_t acc = {0.f, 0.f, 0.f, 0.f};
    const unsigned short* ah_row = dmh + (jt + m) * 512;
    const unsigned short* al_row = dml + (jt + m) * 512;
    const unsigned short* bh_row = Ch + (bt + m) * 512;
    const unsigned short* bl_row = Cl + (bt + m) * 512;
#pragma unroll 4
    for (int k0 = 0; k0 < 512; k0 += 32) {
        int off = k0 + q * 8;
        short8 ah = *(const short8*)(ah_row + off);
        short8 al = *(const short8*)(al_row + off);
        short8 bh = *(const short8*)(bh_row + off);
        short8 bl = *(const short8*)(bl_row + off);
        acc = __builtin_amdgcn_mfma_f32_16x16x32_bf16(ah, bh, acc, 0, 0, 0);
        acc = __builtin_amdgcn_mfma_f32_16x16x32_bf16(ah, bl, acc, 0, 0, 0);
        acc = __builtin_amdgcn_mfma_f32_16x16x32_bf16(al, bh, acc, 0, 0, 0);
    }
#pragma unroll
    for (int r = 0; r < 4; r++) {
        float v = acc[r];
        unsigned short hi = f2bf(v);
        int addr = (bt + m) * 512 + jt + q * 4 + r;   // U^T[b][j]
        UhT[addr] = hi;
        UlT[addr] = f2bf(v - bf2f(hi));
    }
}

// ---------------------------------------------------------------------------
// Stage 2 (MFMA): T[a][b] = sum_j C[a][j] * U[j][b], fused energy reduce.
// B-frag: B[j][b] = U^T[b][j] row-contiguous.
// ---------------------------------------------------------------------------
__global__ __launch_bounds__(256)
void dct2_mfma_kernel(const unsigned short* __restrict__ Ch,
                      const unsigned short* __restrict__ Cl,
                      const unsigned short* __restrict__ UhT,
                      const unsigned short* __restrict__ UlT,
                      const float* __restrict__ unit_len,
                      float* __restrict__ out) {
    __shared__ float red[4];
    int lane = threadIdx.x & 63;
    int wv = threadIdx.x >> 6;
    int tile = blockIdx.x * 4 + wv;
    int at = (tile >> 5) * 16;
    int bt = (tile & 31) * 16;
    int m = lane & 15, q = lane >> 4;
    float4_t acc = {0.f, 0.f, 0.f, 0.f};
    const unsigned short* ah_row = Ch + (at + m) * 512;
    const unsigned short* al_row = Cl + (at + m) * 512;
    const unsigned short* bh_row = UhT + (bt + m) * 512;
    const unsigned short* bl_row = UlT + (bt + m) * 512;
#pragma unroll 4
    for (int k0 = 0; k0 < 512; k0 += 32) {
        int off = k0 + q * 8;
        short8 ah = *(const short8*)(ah_row + off);
        short8 al = *(const short8*)(al_row + off);
        short8 bh = *(const short8*)(bh_row + off);
        short8 bl = *(const short8*)(bl_row + off);
        acc = __builtin_amdgcn_mfma_f32_16x16x32_bf16(ah, bh, acc, 0, 0, 0);
        acc = __builtin_amdgcn_mfma_f32_16x16x32_bf16(ah, bl, acc, 0, 0, 0);
        acc = __builtin_amdgcn_mfma_f32_16x16x32_bf16(al, bh, acc, 0, 0, 0);
    }
    float ratio = unit_len[0] / unit_len[1];
    int b = bt + m;
    float wkb = (float)b * (TWO_PI / (float)NY) * ratio;
    float wyb = (b == 0) ? 1.0f : 2.0f;
    float e = 0.0f;
#pragma unroll
    for (int r = 0; r < 4; r++) {
        int a = at + q * 4 + r;
        float wja = (float)a * (TWO_PI / (float)MX);
        float wsq = wja * wja + wkb * wkb;
        float ps = (a == 0 && b == 0) ? 0.0f : (1.0f / wsq);
        float wxa = (a == 0) ? 1.0f : 2.0f;
        e += wxa * wyb * ps * acc[r] * acc[r];
    }
#pragma unroll
    for (int off = 32; off > 0; off >>= 1) e += __shfl_down(e, off, 64);
    if (lane == 0) red[wv] = e;
    __syncthreads();
    if (threadIdx.x == 0) {
        float t = red[0] + red[1] + red[2] + red[3];
        atomicAdd(out, t * (1.0f / ((float)MX * (float)NY)));
    }
}

extern "C" void kernel_launch(void* const* d_in, const int* in_sizes, int n_in,
                              void* d_out, int out_size, void* d_ws, size_t ws_size,
                              hipStream_t stream) {
    const float2* node_pos  = (const float2*)d_in[0];
    const float2* node_size = (const float2*)d_in[1];
    const float*  node_wt   = (const float*)d_in[2];
    const float*  exp_ratio = (const float*)d_in[3];
    const float*  unit_len  = (const float*)d_in[4];
    const float*  init_dm   = (const float*)d_in[5];
    float* out = (float*)d_out;
    int n = in_sizes[2];

    char* wsb = (char*)d_ws;
    size_t off = 0;
    auto alloc = [&](size_t bytes) { void* p = wsb + off; off = (off + bytes + 255) & ~(size_t)255; return p; };
    float*          dm   = (float*)alloc((size_t)MX * NY * sizeof(float));
    unsigned short* Ch   = (unsigned short*)alloc((size_t)MX * NY * 2);
    unsigned short* Cl   = (unsigned short*)alloc((size_t)MX * NY * 2);
    unsigned short* dmh  = (unsigned short*)alloc((size_t)MX * NY * 2);
    unsigned short* dml  = (unsigned short*)alloc((size_t)MX * NY * 2);
    unsigned short* UhT  = (unsigned short*)alloc((size_t)MX * NY * 2);
    unsigned short* UlT  = (unsigned short*)alloc((size_t)MX * NY * 2);
    unsigned int*   cnt    = (unsigned int*)alloc(NTILES * sizeof(unsigned int));
    unsigned int*   tbase  = (unsigned int*)alloc(NTILES * sizeof(unsigned int));
    unsigned int*   cursor = (unsigned int*)alloc(NTILES * sizeof(unsigned int));
    size_t off_common = off;
    // Tier A: payload arrays.
    float4* pb = (float4*)alloc((size_t)n * sizeof(float4));
    float*  pw = (float*)alloc((size_t)n * sizeof(float));
    bool tierA = (off <= ws_size);
    // Tier B: index arrays (overlay same region).
    off = off_common;
    unsigned int* sorted = (unsigned int*)alloc((size_t)n * sizeof(unsigned int));
    bool tierB = (off <= ws_size);

    hipMemcpyAsync(dm, init_dm, (size_t)MX * NY * sizeof(float),
                   hipMemcpyDeviceToDevice, stream);
    hipMemsetAsync(d_out, 0, sizeof(float), stream);
    gen_cos_kernel<<<(MX * NY) / 256, 256, 0, stream>>>(Ch, Cl);

    if (tierA || tierB) {
        hipMemsetAsync(cnt, 0, NTILES * sizeof(unsigned int), stream);
        int nblk = (n + NPB - 1) / NPB;
        count_kernel<<<nblk, 256, 0, stream>>>(node_pos, node_size, unit_len, cnt, n);
        scan_kernel<<<1, 256, 0, stream>>>(cnt, tbase, cursor);
        if (tierA) {
            place_payload_kernel<<<nblk, 256, 0, stream>>>(
                node_pos, node_size, node_wt, exp_ratio, unit_len, cursor, pb, pw, n);
            accum_payload_kernel<<<NTILES, 256, 0, stream>>>(pb, pw, tbase, cnt, dm);
        } else {
            place_index_kernel<<<nblk, 256, 0, stream>>>(
                node_pos, node_size, unit_len, cursor, sorted, n);
            accum_index_kernel<<<NTILES, 256, 0, stream>>>(
                sorted, tbase, cnt, node_pos, node_size, node_wt, exp_ratio,
                unit_len, dm);
        }
    } else {
        scatter_kernel<<<(n + 255) / 256, 256, 0, stream>>>(
            node_pos, node_size, node_wt, exp_ratio, unit_len, dm, n);
    }

    cvt_dm_kernel<<<(MX * NY) / 256, 256, 0, stream>>>(dm, dmh, dml);
    dct1_mfma_kernel<<<NTILES / 4, 256, 0, stream>>>(dmh, dml, Ch, Cl, UhT, UlT);
    dct2_mfma_kernel<<<NTILES / 4, 256, 0, stream>>>(Ch, Cl, UhT, UlT, unit_len, out);
}

// Round 4
// 287.208 us; speedup vs baseline: 3.1637x; 1.0564x over previous
//
#include <hip/hip_runtime.h>
#include <math.h>

#define MX 512
#define NY 512
#define TWO_PI 6.283185307179586f

#define TILE_SHIFT 4
#define TILES_SIDE 32
#define NTILES 1024
#define NPB 8192
#define LOCAL_DIM 20
#define SLAB_ELEMS (LOCAL_DIM * LOCAL_DIM)   // 400
#define CAP 4096                             // fast-mode per-tile capacity

typedef __attribute__((ext_vector_type(8))) short short8;
typedef __attribute__((ext_vector_type(4))) float float4_t;

__device__ __forceinline__ unsigned short f2bf(float x) {
    union { float f; unsigned u; } v; v.f = x;
    unsigned r = v.u + 0x7fffu + ((v.u >> 16) & 1u);
    return (unsigned short)(r >> 16);
}
__device__ __forceinline__ float bf2f(unsigned short h) {
    union { float f; unsigned u; } v; v.u = ((unsigned)h) << 16;
    return v.f;
}

__device__ __forceinline__ void node_bounds(float2 p, float2 s, float ux, float uy,
                                            float& xl, float& xh, float& yl, float& yh,
                                            float& nw, float& nh) {
    const float SQ2 = 1.41421356237309515f;
    nw = fmaxf(s.x, SQ2 * ux);
    nh = fmaxf(s.y, SQ2 * uy);
    xl = fminf(fmaxf((p.x - 0.5f * nw) / ux, 0.0f), (float)MX);
    xh = fminf(fmaxf((p.x + 0.5f * nw) / ux, 0.0f), (float)MX);
    yl = fminf(fmaxf((p.y - 0.5f * nh) / uy, 0.0f), (float)NY);
    yh = fminf(fmaxf((p.y + 0.5f * nh) / uy, 0.0f), (float)NY);
}

// ---------------------------------------------------------------------------
// Fast mode: base[t] = cursor[t] = t*CAP  (base has NTILES+1 entries).
// ---------------------------------------------------------------------------
__global__ void init_cap_kernel(unsigned int* __restrict__ base,
                                unsigned int* __restrict__ cursor) {
    int t = blockIdx.x * blockDim.x + threadIdx.x;
    if (t <= NTILES) {
        base[t] = (unsigned int)t * CAP;
        if (t < NTILES) cursor[t] = (unsigned int)t * CAP;
    }
}

// ---------------------------------------------------------------------------
// Exact mode K1: count nodes per tile.
// ---------------------------------------------------------------------------
__global__ __launch_bounds__(256)
void count_kernel(const float2* __restrict__ pos, const float2* __restrict__ size,
                  const float* __restrict__ unit_len,
                  unsigned int* __restrict__ cnt, int n) {
    __shared__ unsigned int h[NTILES];
    for (int t = threadIdx.x; t < NTILES; t += 256) h[t] = 0;
    __syncthreads();
    float ux = unit_len[0], uy = unit_len[1];
    int start = blockIdx.x * NPB;
    int end = min(start + NPB, n);
    for (int i = start + (int)threadIdx.x; i < end; i += 256) {
        float xl, xh, yl, yh, nw, nh;
        node_bounds(pos[i], size[i], ux, uy, xl, xh, yl, yh, nw, nh);
        int bx0 = min((int)floorf(xl), MX - 1);
        int by0 = min((int)floorf(yl), NY - 1);
        int t = ((bx0 >> TILE_SHIFT) << 5) | (by0 >> TILE_SHIFT);
        atomicAdd(&h[t], 1u);
    }
    __syncthreads();
    for (int t = threadIdx.x; t < NTILES; t += 256) {
        unsigned int c = h[t];
        if (c) atomicAdd(&cnt[t], c);
    }
}

// ---------------------------------------------------------------------------
// Exact mode K2: exclusive scan; writes base[0..NTILES] and cursor.
// ---------------------------------------------------------------------------
__global__ __launch_bounds__(256)
void scan_kernel(const unsigned int* __restrict__ cnt,
                 unsigned int* __restrict__ base,
                 unsigned int* __restrict__ cursor) {
    __shared__ unsigned int s[256];
    int tid = threadIdx.x;
    unsigned int loc[4];
    unsigned int sum = 0;
#pragma unroll
    for (int k = 0; k < 4; k++) { loc[k] = cnt[tid * 4 + k]; sum += loc[k]; }
    s[tid] = sum;
    __syncthreads();
    for (int off = 1; off < 256; off <<= 1) {
        unsigned int v = (tid >= off) ? s[tid - off] : 0u;
        __syncthreads();
        s[tid] += v;
        __syncthreads();
    }
    unsigned int ex = (tid == 0) ? 0u : s[tid - 1];
#pragma unroll
    for (int k = 0; k < 4; k++) {
        base[tid * 4 + k] = ex;
        cursor[tid * 4 + k] = ex;
        ex += loc[k];
    }
    if (tid == 255) base[NTILES] = ex;
}

// ---------------------------------------------------------------------------
// Place: sequential node reads, scatter (xl,xh,yl,yh | w) payload into
// per-tile segments reserved from cursor. Works for both modes.
// ---------------------------------------------------------------------------
__global__ __launch_bounds__(256)
void place_payload_kernel(const float2* __restrict__ pos, const float2* __restrict__ size,
                          const float* __restrict__ nwt, const float* __restrict__ er,
                          const float* __restrict__ unit_len,
                          const unsigned int* __restrict__ base,
                          unsigned int* __restrict__ cursor,
                          float4* __restrict__ pb, float* __restrict__ pw, int n) {
    __shared__ unsigned int h[NTILES];
    __shared__ unsigned int bb[NTILES];
    for (int t = threadIdx.x; t < NTILES; t += 256) h[t] = 0;
    __syncthreads();
    float ux = unit_len[0], uy = unit_len[1];
    int start = blockIdx.x * NPB;
    int end = min(start + NPB, n);
    unsigned int packed[NPB / 256];
#pragma unroll
    for (int k = 0; k < NPB / 256; k++) {
        int i = start + k * 256 + (int)threadIdx.x;
        if (i < end) {
            float xl, xh, yl, yh, nw, nh;
            node_bounds(pos[i], size[i], ux, uy, xl, xh, yl, yh, nw, nh);
            int bx0 = min((int)floorf(xl), MX - 1);
            int by0 = min((int)floorf(yl), NY - 1);
            unsigned int t = ((bx0 >> TILE_SHIFT) << 5) | (by0 >> TILE_SHIFT);
            packed[k] = (t << 13) | atomicAdd(&h[t], 1u);
        }
    }
    __syncthreads();
    for (int t = threadIdx.x; t < NTILES; t += 256) {
        unsigned int c = h[t];
        if (c) bb[t] = atomicAdd(&cursor[t], c);
    }
    __syncthreads();
#pragma unroll
    for (int k = 0; k < NPB / 256; k++) {
        int i = start + k * 256 + (int)threadIdx.x;
        if (i < end) {
            float2 p = pos[i], s = size[i];
            float xl, xh, yl, yh, nw, nh;
            node_bounds(p, s, ux, uy, xl, xh, yl, yh, nw, nh);
            float w = nwt[i] * er[i] * (s.x * s.y) / (nw * nh);
            unsigned int t = packed[k] >> 13;
            unsigned int dst = bb[t] + (packed[k] & 8191u);
            if (dst < base[t + 1]) {       // capacity guard (no-op in exact mode)
                pb[dst] = make_float4(xl, xh, yl, yh);
                pw[dst] = w;
            }
        }
    }
}

// ---------------------------------------------------------------------------
// Accum: 2 blocks per tile, each accumulates half the segment into a private
// 20x20 LDS tile, then plain-stores it to its slab (no global atomics).
// ---------------------------------------------------------------------------
__global__ __launch_bounds__(256)
void accum_slab_kernel(const float4* __restrict__ pb, const float* __restrict__ pw,
                       const unsigned int* __restrict__ base,
                       const unsigned int* __restrict__ cursor,
                       float* __restrict__ slab) {
    __shared__ float acc[LOCAL_DIM][LOCAL_DIM + 1];
    int t = blockIdx.x >> 1;
    int half = blockIdx.x & 1;
    int tbx = (t >> 5) << TILE_SHIFT;
    int tby = (t & 31) << TILE_SHIFT;
    for (int e = threadIdx.x; e < SLAB_ELEMS; e += 256)
        acc[e / LOCAL_DIM][e % LOCAL_DIM] = 0.0f;
    __syncthreads();

    unsigned int b0 = base[t];
    unsigned int c = min(cursor[t] - b0, base[t + 1] - b0);
    unsigned int chunk = (c + 1) >> 1;
    unsigned int ks = half * chunk;
    unsigned int ke = min(c, ks + chunk);
    for (unsigned int k = ks + threadIdx.x; k < ke; k += 256) {
        float4 b4 = pb[b0 + k];
        float w = pw[b0 + k];
        float xl = b4.x, xh = b4.y, yl = b4.z, yh = b4.w;
        int bx0 = min((int)floorf(xl), MX - 1);
        int by0 = min((int)floorf(yl), NY - 1);
        float oxs[4], oys[4];
        int lxs[4], lys[4];
#pragma unroll
        for (int d = 0; d < 4; d++) {
            int ix = bx0 + d;
            float fx = (float)ix;
            oxs[d] = fmaxf(fminf(xh, fx + 1.0f) - fmaxf(xl, fx), 0.0f);
            lxs[d] = min(max(min(ix, MX - 1) - tbx, 0), LOCAL_DIM - 1);
            int iy = by0 + d;
            float fy = (float)iy;
            oys[d] = fmaxf(fminf(yh, fy + 1.0f) - fmaxf(yl, fy), 0.0f);
            lys[d] = min(max(min(iy, NY - 1) - tby, 0), LOCAL_DIM - 1);
        }
#pragma unroll
        for (int dx = 0; dx < 4; dx++) {
            if (oxs[dx] == 0.0f) continue;
            float wox = w * oxs[dx];
#pragma unroll
            for (int dy = 0; dy < 4; dy++) {
                float v = wox * oys[dy];
                if (v != 0.0f) atomicAdd(&acc[lxs[dx]][lys[dy]], v);
            }
        }
    }
    __syncthreads();
    float* dst = slab + (size_t)blockIdx.x * SLAB_ELEMS;
    for (int e = threadIdx.x; e < SLAB_ELEMS; e += 256)
        dst[e] = acc[e / LOCAL_DIM][e % LOCAL_DIM];
}

// ---------------------------------------------------------------------------
// Combine: dm[gx][gy] = init + sum of <=8 contributing slabs; emit bf16 hi/lo.
// ---------------------------------------------------------------------------
__global__ __launch_bounds__(256)
void combine_kernel(const float* __restrict__ slab,
                    const float* __restrict__ init_dm,
                    unsigned short* __restrict__ dmh,
                    unsigned short* __restrict__ dml) {
    int idx = blockIdx.x * blockDim.x + threadIdx.x;   // gx*512+gy
    int gx = idx >> 9, gy = idx & 511;
    float sum = init_dm[idx];
    int tx0 = gx >> 4, ty0 = gy >> 4;
    int rx = gx & 15, ry = gy & 15;
#pragma unroll
    for (int ax = 0; ax < 2; ax++) {
        int tx = tx0 - ax;
        if (tx < 0 || (ax == 1 && rx > 3)) continue;
        int lx = rx + ax * 16;
#pragma unroll
        for (int ay = 0; ay < 2; ay++) {
            int ty = ty0 - ay;
            if (ty < 0 || (ay == 1 && ry > 3)) continue;
            int ly = ry + ay * 16;
            const float* s0 = slab + ((size_t)((tx << 5) | ty) * 2) * SLAB_ELEMS
                                   + lx * LOCAL_DIM + ly;
            sum += s0[0] + s0[SLAB_ELEMS];
        }
    }
    unsigned short hi = f2bf(sum);
    dmh[idx] = hi;
    dml[idx] = f2bf(sum - bf2f(hi));
}

// ---------------------------------------------------------------------------
// Tier-C fallback: direct global-atomic scatter into fp32 dm.
// ---------------------------------------------------------------------------
__global__ __launch_bounds__(256)
void scatter_kernel(const float2* __restrict__ pos, const float2* __restrict__ size,
                    const float* __restrict__ nwt, const float* __restrict__ er,
                    const float* __restrict__ unit_len,
                    float* __restrict__ dm, int n) {
    int i = blockIdx.x * blockDim.x + threadIdx.x;
    if (i >= n) return;
    float ux = unit_len[0], uy = unit_len[1];
    float2 p = pos[i], s = size[i];
    float xl, xh, yl, yh, nw, nh;
    node_bounds(p, s, ux, uy, xl, xh, yl, yh, nw, nh);
    float w = nwt[i] * er[i] * (s.x * s.y) / (nw * nh);
    int bx0 = (int)floorf(xl);
    int by0 = (int)floorf(yl);
#pragma unroll
    for (int dx = 0; dx < 4; dx++) {
        int ix = bx0 + dx;
        float fx = (float)ix;
        float ox = fmaxf(fminf(xh, fx + 1.0f) - fmaxf(xl, fx), 0.0f);
        if (ox == 0.0f) continue;
        int rowoff = min(max(ix, 0), MX - 1) * NY;
        float wox = w * ox;
#pragma unroll
        for (int dy = 0; dy < 4; dy++) {
            int iy = by0 + dy;
            float fy = (float)iy;
            float oy = fmaxf(fminf(yh, fy + 1.0f) - fmaxf(yl, fy), 0.0f);
            float v = wox * oy;
            if (v != 0.0f) atomicAdd(&dm[rowoff + min(max(iy, 0), NY - 1)], v);
        }
    }
}

__global__ void cvt_dm_kernel(const float* __restrict__ dm,
                              unsigned short* __restrict__ dmh,
                              unsigned short* __restrict__ dml) {
    int idx = blockIdx.x * blockDim.x + threadIdx.x;
    float x = dm[idx];
    unsigned short hi = f2bf(x);
    dmh[idx] = hi;
    dml[idx] = f2bf(x - bf2f(hi));
}

// ---------------------------------------------------------------------------
// DCT cos matrix, bf16 hi/lo.
// ---------------------------------------------------------------------------
__global__ void gen_cos_kernel(unsigned short* __restrict__ Ch,
                               unsigned short* __restrict__ Cl) {
    int idx = blockIdx.x * blockDim.x + threadIdx.x;
    int a = idx >> 9;
    int j = idx & 511;
    float x = cospif((float)(a * (2 * j + 1)) * (1.0f / 1024.0f));
    unsigned short hi = f2bf(x);
    Ch[idx] = hi;
    Cl[idx] = f2bf(x - bf2f(hi));
}

// ---------------------------------------------------------------------------
// Stage 1 (MFMA): U = dm @ C^T, store U^T bf16 hi/lo.
// ---------------------------------------------------------------------------
__global__ __launch_bounds__(256)
void dct1_mfma_kernel(const unsigned short* __restrict__ dmh,
                      const unsigned short* __restrict__ dml,
                      const unsigned short* __restrict__ Ch,
                      const unsigned short* __restrict__ Cl,
                      unsigned short* __restrict__ UhT,
                      unsigned short* __restrict__ UlT) {
    int lane = threadIdx.x & 63;
    int wv = threadIdx.x >> 6;
    int tile = blockIdx.x * 4 + wv;
    int jt = (tile >> 5) * 16;
    int bt = (tile & 31) * 16;
    int m = lane & 15, q = lane >> 4;
    float4_t acc = {0.f, 0.f, 0.f, 0.f};
    const unsigned short* ah_row = dmh + (jt + m) * 512;
    const unsigned short* al_row = dml + (jt + m) * 512;
    const unsigned short* bh_row = Ch + (bt + m) * 512;
    const unsigned short* bl_row = Cl + (bt + m) * 512;
#pragma unroll 4
    for (int k0 = 0; k0 < 512; k0 += 32) {
        int off = k0 + q * 8;
        short8 ah = *(const short8*)(ah_row + off);
        short8 al = *(const short8*)(al_row + off);
        short8 bh = *(const short8*)(bh_row + off);
        short8 bl = *(const short8*)(bl_row + off);
        acc = __builtin_amdgcn_mfma_f32_16x16x32_bf16(ah, bh, acc, 0, 0, 0);
        acc = __builtin_amdgcn_mfma_f32_16x16x32_bf16(ah, bl, acc, 0, 0, 0);
        acc = __builtin_amdgcn_mfma_f32_16x16x32_bf16(al, bh, acc, 0, 0, 0);
    }
#pragma unroll
    for (int r = 0; r < 4; r++) {
        float v = acc[r];
        unsigned short hi = f2bf(v);
        int addr = (bt + m) * 512 + jt + q * 4 + r;
        UhT[addr] = hi;
        UlT[addr] = f2bf(v - bf2f(hi));
    }
}

// ---------------------------------------------------------------------------
// Stage 2 (MFMA): T = C @ U fused with energy reduce.
// ---------------------------------------------------------------------------
__global__ __launch_bounds__(256)
void dct2_mfma_kernel(const unsigned short* __restrict__ Ch,
                      const unsigned short* __restrict__ Cl,
                      const unsigned short* __restrict__ UhT,
                      const unsigned short* __restrict__ UlT,
                      const float* __restrict__ unit_len,
                      float* __restrict__ out) {
    __shared__ float red[4];
    int lane = threadIdx.x & 63;
    int wv = threadIdx.x >> 6;
    int tile = blockIdx.x * 4 + wv;
    int at = (tile >> 5) * 16;
    int bt = (tile & 31) * 16;
    int m = lane & 15, q = lane >> 4;
    float4_t acc = {0.f, 0.f, 0.f, 0.f};
    const unsigned short* ah_row = Ch + (at + m) * 512;
    const unsigned short* al_row = Cl + (at + m) * 512;
    const unsigned short* bh_row = UhT + (bt + m) * 512;
    const unsigned short* bl_row = UlT + (bt + m) * 512;
#pragma unroll 4
    for (int k0 = 0; k0 < 512; k0 += 32) {
        int off = k0 + q * 8;
        short8 ah = *(const short8*)(ah_row + off);
        short8 al = *(const short8*)(al_row + off);
        short8 bh = *(const short8*)(bh_row + off);
        short8 bl = *(const short8*)(bl_row + off);
        acc = __builtin_amdgcn_mfma_f32_16x16x32_bf16(ah, bh, acc, 0, 0, 0);
        acc = __builtin_amdgcn_mfma_f32_16x16x32_bf16(ah, bl, acc, 0, 0, 0);
        acc = __builtin_amdgcn_mfma_f32_16x16x32_bf16(al, bh, acc, 0, 0, 0);
    }
    float ratio = unit_len[0] / unit_len[1];
    int b = bt + m;
    float wkb = (float)b * (TWO_PI / (float)NY) * ratio;
    float wyb = (b == 0) ? 1.0f : 2.0f;
    float e = 0.0f;
#pragma unroll
    for (int r = 0; r < 4; r++) {
        int a = at + q * 4 + r;
        float wja = (float)a * (TWO_PI / (float)MX);
        float wsq = wja * wja + wkb * wkb;
        float ps = (a == 0 && b == 0) ? 0.0f : (1.0f / wsq);
        float wxa = (a == 0) ? 1.0f : 2.0f;
        e += wxa * wyb * ps * acc[r] * acc[r];
    }
#pragma unroll
    for (int off = 32; off > 0; off >>= 1) e += __shfl_down(e, off, 64);
    if (lane == 0) red[wv] = e;
    __syncthreads();
    if (threadIdx.x == 0) {
        float t = red[0] + red[1] + red[2] + red[3];
        atomicAdd(out, t * (1.0f / ((float)MX * (float)NY)));
    }
}

extern "C" void kernel_launch(void* const* d_in, const int* in_sizes, int n_in,
                              void* d_out, int out_size, void* d_ws, size_t ws_size,
                              hipStream_t stream) {
    const float2* node_pos  = (const float2*)d_in[0];
    const float2* node_size = (const float2*)d_in[1];
    const float*  node_wt   = (const float*)d_in[2];
    const float*  exp_ratio = (const float*)d_in[3];
    const float*  unit_len  = (const float*)d_in[4];
    const float*  init_dm   = (const float*)d_in[5];
    float* out = (float*)d_out;
    int n = in_sizes[2];

    char* wsb = (char*)d_ws;
    size_t off = 0;
    auto alloc = [&](size_t bytes) { void* p = wsb + off; off = (off + bytes + 255) & ~(size_t)255; return p; };
    unsigned short* Ch   = (unsigned short*)alloc((size_t)MX * NY * 2);
    unsigned short* Cl   = (unsigned short*)alloc((size_t)MX * NY * 2);
    unsigned short* dmh  = (unsigned short*)alloc((size_t)MX * NY * 2);
    unsigned short* dml  = (unsigned short*)alloc((size_t)MX * NY * 2);
    unsigned short* UhT  = (unsigned short*)alloc((size_t)MX * NY * 2);
    unsigned short* UlT  = (unsigned short*)alloc((size_t)MX * NY * 2);
    float*          dm     = (float*)alloc((size_t)MX * NY * sizeof(float));  // tier C only
    unsigned int*   cnt    = (unsigned int*)alloc(NTILES * sizeof(unsigned int));
    unsigned int*   tbase  = (unsigned int*)alloc((NTILES + 1) * sizeof(unsigned int));
    unsigned int*   cursor = (unsigned int*)alloc(NTILES * sizeof(unsigned int));
    float*          slab   = (float*)alloc((size_t)NTILES * 2 * SLAB_ELEMS * sizeof(float));
    size_t off_common = off;
    // Tier FAST: fixed-capacity payload (no count pass).
    float4* pbF = (float4*)alloc((size_t)NTILES * CAP * sizeof(float4));
    float*  pwF = (float*)alloc((size_t)NTILES * CAP * sizeof(float));
    bool tierFast = (off <= ws_size);
    // Tier EXACT: n-sized payload (count + scan).
    off = off_common;
    float4* pbE = (float4*)alloc((size_t)n * sizeof(float4));
    float*  pwE = (float*)alloc((size_t)n * sizeof(float));
    bool tierExact = (off <= ws_size);

    hipMemsetAsync(d_out, 0, sizeof(float), stream);
    gen_cos_kernel<<<(MX * NY) / 256, 256, 0, stream>>>(Ch, Cl);

    if (tierFast || tierExact) {
        float4* pb = tierFast ? pbF : pbE;
        float*  pw = tierFast ? pwF : pwE;
        int nblk = (n + NPB - 1) / NPB;
        if (tierFast) {
            init_cap_kernel<<<5, 256, 0, stream>>>(tbase, cursor);
        } else {
            hipMemsetAsync(cnt, 0, NTILES * sizeof(unsigned int), stream);
            count_kernel<<<nblk, 256, 0, stream>>>(node_pos, node_size, unit_len, cnt, n);
            scan_kernel<<<1, 256, 0, stream>>>(cnt, tbase, cursor);
        }
        place_payload_kernel<<<nblk, 256, 0, stream>>>(
            node_pos, node_size, node_wt, exp_ratio, unit_len, tbase, cursor,
            pb, pw, n);
        accum_slab_kernel<<<NTILES * 2, 256, 0, stream>>>(pb, pw, tbase, cursor, slab);
        combine_kernel<<<(MX * NY) / 256, 256, 0, stream>>>(slab, init_dm, dmh, dml);
    } else {
        hipMemcpyAsync(dm, init_dm, (size_t)MX * NY * sizeof(float),
                       hipMemcpyDeviceToDevice, stream);
        scatter_kernel<<<(n + 255) / 256, 256, 0, stream>>>(
            node_pos, node_size, node_wt, exp_ratio, unit_len, dm, n);
        cvt_dm_kernel<<<(MX * NY) / 256, 256, 0, stream>>>(dm, dmh, dml);
    }

    dct1_mfma_kernel<<<NTILES / 4, 256, 0, stream>>>(dmh, dml, Ch, Cl, UhT, UlT);
    dct2_mfma_kernel<<<NTILES / 4, 256, 0, stream>>>(Ch, Cl, UhT, UlT, unit_len, out);
}